// Round 24
// baseline (21.946 us; speedup 1.0000x reference)
//
#include <hip/hip_runtime.h>
#include <float.h>

#define BATCH 8
#define NPTS 4096
#define BLK 512               // 8 waves
#define TOCT 512              // adv targets per block (one octant)
#define NOCT 8                // octants
#define NRG 8                 // rowgroups of 512 rows

typedef __attribute__((ext_vector_type(8))) short short8;      // 8 bf16
typedef __attribute__((ext_vector_type(16))) float floatx16;   // 32x32 MFMA acc

union U4S8 { uint4 u; short8 s; };
__device__ inline short8 asS8(uint4 u) { U4S8 t; t.u = u; return t.s; }

// round-to-nearest-even f32 -> bf16 bits
__device__ inline unsigned short f2bf(float f) {
    unsigned u = __float_as_uint(f);
    return (unsigned short)((u + 0x7FFFu + ((u >> 16) & 1u)) >> 16);
}
__device__ inline float bf2f(unsigned short h) {
    return __uint_as_float(((unsigned)h) << 16);
}
__device__ inline unsigned flag_token(int i) {
    return 0x9E3779B9u * (unsigned)(i + 7);   // never 0xAAAAAAAA poison
}

#define SBAR() __builtin_amdgcn_sched_barrier(0)

// 16-element register tree min (compiler fuses pairs into v_min3)
__device__ inline float tree16(const floatx16& v) {
    float t0 = fminf(fminf(v[0], v[1]), fminf(v[2], v[3]));
    float t1 = fminf(fminf(v[4], v[5]), fminf(v[6], v[7]));
    float t2 = fminf(fminf(v[8], v[9]), fminf(v[10], v[11]));
    float t3 = fminf(fminf(v[12], v[13]), fminf(v[14], v[15]));
    return fminf(fminf(t0, t1), fminf(t2, t3));
}

// ---------------------------------------------------------------------------
// SYMMETRIC kernel: d1 = row-min, d2 = col-min of the SAME D = dist(ori,adv)
// -> D computed ONCE per batch: MFMAs/staging/LDS-reads HALVE vs R22 (18.9us).
// Grid = 512 = (b(8), rowgroup(8), octant(8)); block = 512 ori rows x 512
// adv cols; 8 waves x 2 bands of 32 rows; R22's proven deferred cross-band
// pipeline (8 tile-pairs). Col path uses the verified C/D mapping
// (col = lane&31; rows split across regs + kh): per tile, tree16 per band
// + cross-band min + shfl_xor(32) (merges kh halves) = col-min over the
// wave's 64 rows -> cmin[wave][col] in LDS (conflict-free), min'd across
// 8 waves at block end -> cpart[b][rg][col].
// Numerics identical to rounds 7-23 (absmax 0.0): K=16 hi/lo bf16 encoding
// folds |q|^2 + |t|^2 - 2q.t into one mfma_f32_32x32x16_bf16;
// C/D row = (r&3) + 8*(r>>2) + 4*kh (verified m74/m101).
// ---------------------------------------------------------------------------
__global__ __launch_bounds__(BLK, 4) void chamfer_sym(
        const float* __restrict__ ori, const float* __restrict__ adv,
        float* __restrict__ rpart, float* __restrict__ cpart) {
    __shared__ uint4 fr[2 * TOCT];     // 16 KB: [kh][target]
    __shared__ float cmin[8][TOCT];    // 16 KB: per-wave col mins

    int bx = blockIdx.x;               // 0..511
    int oct = bx & (NOCT - 1);
    int rg  = (bx >> 3) & (NRG - 1);
    int b   = bx >> 6;                 // 0..7

    // ---- stage this octant's 512 adv targets as BOTH B-frag variants ----
    {
        const float* tx = adv + (b * 3 + 0) * NPTS;
        const float* ty = adv + (b * 3 + 1) * NPTS;
        const float* tz = adv + (b * 3 + 2) * NPTS;
        int p = threadIdx.x;           // 512 threads, 512 targets
        int m = oct * TOCT + p;
        float x = tx[m], y = ty[m], z = tz[m];
        float n2 = fmaf(x, x, fmaf(y, y, z * z));
        unsigned short hx = f2bf(x), hy = f2bf(y), hz = f2bf(z);
        unsigned short lx = f2bf(x - bf2f(hx));
        unsigned short ly = f2bf(y - bf2f(hy));
        unsigned short lz = f2bf(z - bf2f(hz));
        unsigned short h2 = f2bf(n2);
        unsigned short l2 = f2bf(n2 - bf2f(h2));
        uint4 v0;   // kh=0: B rows 0..7 = [thi(3), tlo(3), n2h, n2l]
        v0.x = (unsigned)hx | ((unsigned)hy << 16);
        v0.y = (unsigned)hz | ((unsigned)lx << 16);
        v0.z = (unsigned)ly | ((unsigned)lz << 16);
        v0.w = (unsigned)h2 | ((unsigned)l2 << 16);
        uint4 v1;   // kh=1: B rows 8..15 = [thi(3), 1, 1, 0,0,0]
        v1.x = v0.x;
        v1.y = (unsigned)hz | (0x3F80u << 16);
        v1.z = 0x00003F80u;
        v1.w = 0u;
        fr[p] = v0;
        fr[TOCT + p] = v1;
    }

    // ---- per-wave A fragments: 2 bands of 32 ori rows ----
    int w = threadIdx.x >> 6;          // wave 0..7
    int l = threadIdx.x & 63;
    int lrow = l & 31;
    int kh = l >> 5;

    short8 afrag0, afrag1;
    #pragma unroll
    for (int bi = 0; bi < 2; ++bi) {
        int q = rg * 512 + (w * 2 + bi) * 32 + lrow;
        float x = ori[(b * 3 + 0) * NPTS + q];
        float y = ori[(b * 3 + 1) * NPTS + q];
        float z = ori[(b * 3 + 2) * NPTS + q];
        float n2 = fmaf(x, x, fmaf(y, y, z * z));
        unsigned short hx = f2bf(x), hy = f2bf(y), hz = f2bf(z);
        unsigned short lx = f2bf(x - bf2f(hx));
        unsigned short ly = f2bf(y - bf2f(hy));
        unsigned short lz = f2bf(z - bf2f(hz));
        unsigned short h2 = f2bf(n2);
        unsigned short l2 = f2bf(n2 - bf2f(h2));
        unsigned short mhx = f2bf(-2.0f * bf2f(hx));
        unsigned short mhy = f2bf(-2.0f * bf2f(hy));
        unsigned short mhz = f2bf(-2.0f * bf2f(hz));
        unsigned short mlx = f2bf(-2.0f * bf2f(lx));
        unsigned short mly = f2bf(-2.0f * bf2f(ly));
        unsigned short mlz = f2bf(-2.0f * bf2f(lz));
        const unsigned short one = 0x3F80;
        union { unsigned short us[8]; short8 s8; } A;
        if (kh == 0) {
            A.us[0] = mhx; A.us[1] = mhy; A.us[2] = mhz;
            A.us[3] = mhx; A.us[4] = mhy; A.us[5] = mhz;
            A.us[6] = one; A.us[7] = one;
        } else {
            A.us[0] = mlx; A.us[1] = mly; A.us[2] = mlz;
            A.us[3] = h2;  A.us[4] = l2;
            A.us[5] = 0;   A.us[6] = 0;   A.us[7] = 0;
        }
        if (bi == 0) afrag0 = A.s8; else afrag1 = A.s8;
    }
    __syncthreads();

    floatx16 zero, rmn0, rmn1;
    #pragma unroll
    for (int r = 0; r < 16; ++r) { zero[r] = 0.0f; rmn0[r] = FLT_MAX; rmn1[r] = FLT_MAX; }

    const uint4* tp = fr + kh * TOCT + lrow;
    float* cmw = cmin[w];

    // ---- deferred cross-band pipeline over 8 tile-pairs + col-min ----
    {
        uint4 f0 = tp[0], f1 = tp[1 << 5];
        floatx16 a0 = __builtin_amdgcn_mfma_f32_32x32x16_bf16(afrag0, asS8(f0), zero, 0, 0, 0);
        floatx16 a1 = __builtin_amdgcn_mfma_f32_32x32x16_bf16(afrag0, asS8(f1), zero, 0, 0, 0);
        uint4 fn0 = tp[2 << 5], fn1 = tp[3 << 5];
        #pragma unroll
        for (int r = 0; r < 16; ++r)
            rmn0[r] = fminf(fminf(rmn0[r], a0[r]), a1[r]);   // -> v_min3
        float ca0 = tree16(a0), ca1 = tree16(a1);            // band0 col mins
        floatx16 c0 = __builtin_amdgcn_mfma_f32_32x32x16_bf16(afrag1, asS8(f0), zero, 0, 0, 0);
        floatx16 c1 = __builtin_amdgcn_mfma_f32_32x32x16_bf16(afrag1, asS8(f1), zero, 0, 0, 0);
        f0 = fn0; f1 = fn1;

        #pragma unroll 1
        for (int ct = 2; ct < 16; ct += 2) {
            // phase 1: consume band1 of previous pair (tiles ct-2, ct-1)
            #pragma unroll
            for (int r = 0; r < 16; ++r)
                rmn1[r] = fminf(fminf(rmn1[r], c0[r]), c1[r]);
            float cc0 = fminf(ca0, tree16(c0));
            float cc1 = fminf(ca1, tree16(c1));
            cc0 = fminf(cc0, __shfl_xor(cc0, 32));   // merge kh halves
            cc1 = fminf(cc1, __shfl_xor(cc1, 32));
            if (l < 32) {
                cmw[((ct - 2) << 5) + l] = cc0;
                cmw[((ct - 1) << 5) + l] = cc1;
            }
            SBAR();
            // phase 2: issue band0 of current pair
            a0 = __builtin_amdgcn_mfma_f32_32x32x16_bf16(afrag0, asS8(f0), zero, 0, 0, 0);
            a1 = __builtin_amdgcn_mfma_f32_32x32x16_bf16(afrag0, asS8(f1), zero, 0, 0, 0);
            SBAR();
            // phase 3: prefetch next pair (wraps harmlessly on last iter)
            int nt = (ct + 2) & 15;
            fn0 = tp[nt << 5]; fn1 = tp[(nt + 1) << 5];
            SBAR();
            // phase 4: consume band0
            #pragma unroll
            for (int r = 0; r < 16; ++r)
                rmn0[r] = fminf(fminf(rmn0[r], a0[r]), a1[r]);
            ca0 = tree16(a0); ca1 = tree16(a1);
            SBAR();
            // phase 5: issue band1 (consumed next iteration)
            c0 = __builtin_amdgcn_mfma_f32_32x32x16_bf16(afrag1, asS8(f0), zero, 0, 0, 0);
            c1 = __builtin_amdgcn_mfma_f32_32x32x16_bf16(afrag1, asS8(f1), zero, 0, 0, 0);
            SBAR();
            f0 = fn0; f1 = fn1;
        }
        // epilogue: last band1 pair (tiles 14,15)
        #pragma unroll
        for (int r = 0; r < 16; ++r)
            rmn1[r] = fminf(fminf(rmn1[r], c0[r]), c1[r]);
        float cc0 = fminf(ca0, tree16(c0));
        float cc1 = fminf(ca1, tree16(c1));
        cc0 = fminf(cc0, __shfl_xor(cc0, 32));
        cc1 = fminf(cc1, __shfl_xor(cc1, 32));
        if (l < 32) {
            cmw[(14 << 5) + l] = cc0;
            cmw[(15 << 5) + l] = cc1;
        }
    }

    // ---- register-folding butterfly row-min (17 swizzles/band) ----
    bool b0 = (l & 1), b1 = (l & 2), b2 = (l & 4), b3 = (l & 8);

#define FOLD(v)                                                                \
    {                                                                          \
        _Pragma("unroll")                                                      \
        for (int i = 0; i < 8; ++i) {                                          \
            float send = b0 ? v[i] : v[i + 8];                                 \
            float recv = __shfl_xor(send, 1);                                  \
            v[i] = fminf(b0 ? v[i + 8] : v[i], recv);                          \
        }                                                                      \
        _Pragma("unroll")                                                      \
        for (int i = 0; i < 4; ++i) {                                          \
            float send = b1 ? v[i] : v[i + 4];                                 \
            float recv = __shfl_xor(send, 2);                                  \
            v[i] = fminf(b1 ? v[i + 4] : v[i], recv);                          \
        }                                                                      \
        _Pragma("unroll")                                                      \
        for (int i = 0; i < 2; ++i) {                                          \
            float send = b2 ? v[i] : v[i + 2];                                 \
            float recv = __shfl_xor(send, 4);                                  \
            v[i] = fminf(b2 ? v[i + 2] : v[i], recv);                          \
        }                                                                      \
        {                                                                      \
            float send = b3 ? v[0] : v[1];                                     \
            float recv = __shfl_xor(send, 8);                                  \
            v[0] = fminf(b3 ? v[1] : v[0], recv);                              \
        }                                                                      \
        v[0] = fminf(v[0], __shfl_xor(v[0], 16));                              \
    }

    FOLD(rmn0);
    FOLD(rmn1);
#undef FOLD

    // lane g = l&15 holds reg rr = bitrev4(g); row-in-band = (rr&3)+8*(rr>>2)+4*kh
    if ((l & 16) == 0) {
        int g = l & 15;
        int rr = ((g & 1) << 3) | ((g & 2) << 1) | ((g & 4) >> 1) | ((g & 8) >> 3);
        int rowin = (rr & 3) + 8 * (rr >> 2) + 4 * kh;
        float* base = rpart + (((size_t)(b * NOCT + oct)) << 12) + rg * 512;
        base[(w * 2 + 0) * 32 + rowin] = rmn0[0];
        base[(w * 2 + 1) * 32 + rowin] = rmn1[0];
    }

    // ---- block col epilogue: min across the 8 waves' planes ----
    __syncthreads();
    {
        int c = threadIdx.x;           // 512 threads, 512 cols
        float m = cmin[0][c];
        #pragma unroll
        for (int ww = 1; ww < 8; ++ww) m = fminf(m, cmin[ww][c]);
        cpart[(((size_t)(b * NRG + rg)) << 12) + oct * TOCT + c] = m;
    }
}

// ---------------------------------------------------------------------------
// Combine: 128 blocks. cb<64: d1 rows (b=cb>>3, slice=cb&7; min over 8
// octant planes). cb>=64: d2 cols (min over 8 rowgroup planes). Clamp >=0,
// fixed-order sum -> pb[cb] + token flag. Block 0 spins on all 128 flags
// (R9-proven) and finalizes out[0]. Bit-identical every replay.
// ---------------------------------------------------------------------------
__global__ __launch_bounds__(256) void combine_kernel(
        const float* __restrict__ rpart, const float* __restrict__ cpart,
        float* __restrict__ pb, unsigned* __restrict__ flags,
        float* __restrict__ out) {
    __shared__ float ws[4];
    __shared__ float sh[128 + 16];
    int cb = blockIdx.x;               // 0..127
    int d2 = cb >> 6;                  // 0: rows, 1: cols
    int idx = cb & 63;
    int b = idx >> 3, slice = idx & 7;
    const float* p = (d2 ? cpart : rpart) + ((size_t)(b * 8) << 12);
    float s = 0.0f;
    #pragma unroll
    for (int k = 0; k < 2; ++k) {
        int e = slice * 512 + k * 256 + threadIdx.x;
        float m = p[e];
        #pragma unroll
        for (int pl = 1; pl < 8; ++pl)
            m = fminf(m, p[((size_t)pl << 12) + e]);
        s += fmaxf(m, 0.0f);
    }
    for (int off = 32; off > 0; off >>= 1) s += __shfl_down(s, off);
    int wid = threadIdx.x >> 6, lane = threadIdx.x & 63;
    if (lane == 0) ws[wid] = s;
    __syncthreads();
    if (threadIdx.x == 0) {
        float t = ws[0] + ws[1] + ws[2] + ws[3];
        atomicExch((unsigned*)(pb + cb), __float_as_uint(t));
        __threadfence();
        atomicExch(flags + cb, flag_token(cb));
    }

    if (cb == 0) {
        __syncthreads();
        int t = threadIdx.x;
        if (t < 128) {
            unsigned want = flag_token(t);
            while (atomicAdd(flags + t, 0u) != want) {
                __builtin_amdgcn_s_sleep(1);
            }
            sh[t] = __uint_as_float(atomicAdd((unsigned*)(pb + t), 0u));
        }
        __syncthreads();
        if (t < 16) {   // t = half*8 + b
            int half = t >> 3, bb = t & 7;
            float a = 0.0f;
            #pragma unroll
            for (int ss = 0; ss < 8; ++ss) a += sh[half * 64 + bb * 8 + ss];
            sh[128 + half * 8 + bb] = a;
        }
        __syncthreads();
        if (t == 0) {
            float acc = 0.0f;
            #pragma unroll
            for (int bb = 0; bb < BATCH; ++bb)
                acc += fmaxf(sh[128 + bb], sh[128 + 8 + bb]);
            out[0] = acc * (1.0f / (float)NPTS) * (1.0f / (float)BATCH);
        }
    }
}

extern "C" void kernel_launch(void* const* d_in, const int* in_sizes, int n_in,
                              void* d_out, int out_size, void* d_ws, size_t ws_size,
                              hipStream_t stream) {
    const float* ori = (const float*)d_in[0];
    const float* adv = (const float*)d_in[1];
    float* out = (float*)d_out;

    // ws: rpart[8][8][4096] (1 MB) | cpart[8][8][4096] (1 MB) | pb[128] | flags[128]
    float* rpart = (float*)d_ws;
    float* cpart = rpart + (size_t)BATCH * NOCT * NPTS;
    float* pb = cpart + (size_t)BATCH * NRG * NPTS;
    unsigned* flags = (unsigned*)(pb + 128);

    chamfer_sym<<<BATCH * NRG * NOCT, BLK, 0, stream>>>(ori, adv, rpart, cpart);
    combine_kernel<<<128, 256, 0, stream>>>(rpart, cpart, pb, flags, out);
}

// Round 25
// 21.719 us; speedup vs baseline: 1.0104x; 1.0104x over previous
//
#include <hip/hip_runtime.h>
#include <float.h>

#define BATCH 8
#define NPTS 4096
#define BLK 512               // 8 waves
#define THALF 1024            // targets per block (one quarter)
#define NH 4                  // target quarters
#define NRG 8                 // rowgroups of 512 rows

typedef __attribute__((ext_vector_type(8))) short short8;      // 8 bf16
typedef __attribute__((ext_vector_type(16))) float floatx16;   // 32x32 MFMA acc

union U4S8 { uint4 u; short8 s; };
__device__ inline short8 asS8(uint4 u) { U4S8 t; t.u = u; return t.s; }

// round-to-nearest-even f32 -> bf16 bits
__device__ inline unsigned short f2bf(float f) {
    unsigned u = __float_as_uint(f);
    return (unsigned short)((u + 0x7FFFu + ((u >> 16) & 1u)) >> 16);
}
__device__ inline float bf2f(unsigned short h) {
    return __uint_as_float(((unsigned)h) << 16);
}
__device__ inline unsigned flag_token(int i) {
    return 0x9E3779B9u * (unsigned)(i + 7);   // never 0xAAAAAAAA poison
}

#define SBAR() __builtin_amdgcn_sched_barrier(0)

// ---------------------------------------------------------------------------
// Main kernel: R22's champion body (18.9us, absmax 0.0) with TWO epilogue
// changes only: (1) clamp >=0 applied to the per-quarter row-min in-kernel
// (max commutes with the cross-quarter min: max(min(a,b),0) =
// min(max(a,0),max(b,0)) -- exact); (2) rfin layout is quarter-contiguous
// [dirb][row][quarter], so combine reads ONE coalesced float4 per row
// instead of 4 loads at 16KB stride (the last clearly-suboptimal cost).
// Grid = 512 = (dirb(16), rowgroup(8), quarter(4)); 8 waves x 2 bands;
// both kh-variant B-frags precomputed in LDS (32 KB); deferred cross-band
// MFMA pipeline with sched_barrier(0) phase pins; K=16 hi/lo bf16 encoding
// (absmax 0.0, rounds 7-24); C/D row = (r&3)+8*(r>>2)+4*kh (m74/m101).
// ---------------------------------------------------------------------------
__global__ __launch_bounds__(BLK, 4) void chamfer_partial(
        const float* __restrict__ ori, const float* __restrict__ adv,
        float* __restrict__ rfin) {
    __shared__ uint4 fr[2 * THALF];   // 32 KB: [kh][target]

    int bx = blockIdx.x;               // 0..511
    int half = bx & (NH - 1);
    int rowgroup = (bx >> 2) & (NRG - 1);
    int dirb = bx >> 5;                // 0..15
    int b = dirb & 7;
    int dir = dirb >> 3;

    const float* qsrc = dir ? adv : ori;   // dir0: ori->adv, dir1: adv->ori
    const float* tsrc = dir ? ori : adv;

    // ---- stage this quarter's 1024 targets as BOTH B-frag variants ----
    {
        const float* tx = tsrc + (b * 3 + 0) * NPTS;
        const float* ty = tsrc + (b * 3 + 1) * NPTS;
        const float* tz = tsrc + (b * 3 + 2) * NPTS;
        #pragma unroll
        for (int i = 0; i < THALF / BLK; ++i) {
            int p = threadIdx.x + i * BLK;
            int m = half * THALF + p;
            float x = tx[m], y = ty[m], z = tz[m];
            float n2 = fmaf(x, x, fmaf(y, y, z * z));
            unsigned short hx = f2bf(x), hy = f2bf(y), hz = f2bf(z);
            unsigned short lx = f2bf(x - bf2f(hx));
            unsigned short ly = f2bf(y - bf2f(hy));
            unsigned short lz = f2bf(z - bf2f(hz));
            unsigned short h2 = f2bf(n2);
            unsigned short l2 = f2bf(n2 - bf2f(h2));
            uint4 v0;   // kh=0: B rows 0..7 = [thi(3), tlo(3), n2h, n2l]
            v0.x = (unsigned)hx | ((unsigned)hy << 16);
            v0.y = (unsigned)hz | ((unsigned)lx << 16);
            v0.z = (unsigned)ly | ((unsigned)lz << 16);
            v0.w = (unsigned)h2 | ((unsigned)l2 << 16);
            uint4 v1;   // kh=1: B rows 8..15 = [thi(3), 1, 1, 0,0,0]
            v1.x = v0.x;
            v1.y = (unsigned)hz | (0x3F80u << 16);
            v1.z = 0x00003F80u;
            v1.w = 0u;
            fr[p] = v0;
            fr[THALF + p] = v1;
        }
    }

    // ---- per-wave A fragments: 2 bands of 32 rows ----
    int w = threadIdx.x >> 6;          // wave 0..7
    int l = threadIdx.x & 63;
    int lrow = l & 31;
    int kh = l >> 5;

    short8 afrag0, afrag1;
    #pragma unroll
    for (int bi = 0; bi < 2; ++bi) {
        int q = rowgroup * 512 + (w * 2 + bi) * 32 + lrow;
        float x = qsrc[(b * 3 + 0) * NPTS + q];
        float y = qsrc[(b * 3 + 1) * NPTS + q];
        float z = qsrc[(b * 3 + 2) * NPTS + q];
        float n2 = fmaf(x, x, fmaf(y, y, z * z));
        unsigned short hx = f2bf(x), hy = f2bf(y), hz = f2bf(z);
        unsigned short lx = f2bf(x - bf2f(hx));
        unsigned short ly = f2bf(y - bf2f(hy));
        unsigned short lz = f2bf(z - bf2f(hz));
        unsigned short h2 = f2bf(n2);
        unsigned short l2 = f2bf(n2 - bf2f(h2));
        unsigned short mhx = f2bf(-2.0f * bf2f(hx));
        unsigned short mhy = f2bf(-2.0f * bf2f(hy));
        unsigned short mhz = f2bf(-2.0f * bf2f(hz));
        unsigned short mlx = f2bf(-2.0f * bf2f(lx));
        unsigned short mly = f2bf(-2.0f * bf2f(ly));
        unsigned short mlz = f2bf(-2.0f * bf2f(lz));
        const unsigned short one = 0x3F80;
        union { unsigned short us[8]; short8 s8; } A;
        if (kh == 0) {
            A.us[0] = mhx; A.us[1] = mhy; A.us[2] = mhz;
            A.us[3] = mhx; A.us[4] = mhy; A.us[5] = mhz;
            A.us[6] = one; A.us[7] = one;
        } else {
            A.us[0] = mlx; A.us[1] = mly; A.us[2] = mlz;
            A.us[3] = h2;  A.us[4] = l2;
            A.us[5] = 0;   A.us[6] = 0;   A.us[7] = 0;
        }
        if (bi == 0) afrag0 = A.s8; else afrag1 = A.s8;
    }
    __syncthreads();

    floatx16 zero, rmn0, rmn1;
    #pragma unroll
    for (int r = 0; r < 16; ++r) { zero[r] = 0.0f; rmn0[r] = FLT_MAX; rmn1[r] = FLT_MAX; }

    const uint4* tp = fr + kh * THALF + lrow;

    // ---- deferred cross-band pipeline, schedule pinned via sched_barrier ----
    {
        uint4 f0 = tp[0], f1 = tp[1 << 5];
        floatx16 a0 = __builtin_amdgcn_mfma_f32_32x32x16_bf16(afrag0, asS8(f0), zero, 0, 0, 0);
        floatx16 a1 = __builtin_amdgcn_mfma_f32_32x32x16_bf16(afrag0, asS8(f1), zero, 0, 0, 0);
        uint4 fn0 = tp[2 << 5], fn1 = tp[3 << 5];
        #pragma unroll
        for (int r = 0; r < 16; ++r)
            rmn0[r] = fminf(fminf(rmn0[r], a0[r]), a1[r]);   // -> v_min3
        floatx16 c0 = __builtin_amdgcn_mfma_f32_32x32x16_bf16(afrag1, asS8(f0), zero, 0, 0, 0);
        floatx16 c1 = __builtin_amdgcn_mfma_f32_32x32x16_bf16(afrag1, asS8(f1), zero, 0, 0, 0);
        f0 = fn0; f1 = fn1;

        #pragma unroll 1
        for (int ct = 2; ct < 32; ct += 2) {
            // phase 1: consume band1 of previous tile-pair
            #pragma unroll
            for (int r = 0; r < 16; ++r)
                rmn1[r] = fminf(fminf(rmn1[r], c0[r]), c1[r]);
            SBAR();
            // phase 2: issue band0 of current pair
            a0 = __builtin_amdgcn_mfma_f32_32x32x16_bf16(afrag0, asS8(f0), zero, 0, 0, 0);
            a1 = __builtin_amdgcn_mfma_f32_32x32x16_bf16(afrag0, asS8(f1), zero, 0, 0, 0);
            SBAR();
            // phase 3: prefetch next pair (wraps harmlessly on last iter)
            int nt = (ct + 2) & 31;
            fn0 = tp[nt << 5]; fn1 = tp[(nt + 1) << 5];
            SBAR();
            // phase 4: consume band0 (MFMA latency hidden by phase 3)
            #pragma unroll
            for (int r = 0; r < 16; ++r)
                rmn0[r] = fminf(fminf(rmn0[r], a0[r]), a1[r]);
            SBAR();
            // phase 5: issue band1 of current pair (consumed next iteration)
            c0 = __builtin_amdgcn_mfma_f32_32x32x16_bf16(afrag1, asS8(f0), zero, 0, 0, 0);
            c1 = __builtin_amdgcn_mfma_f32_32x32x16_bf16(afrag1, asS8(f1), zero, 0, 0, 0);
            SBAR();
            f0 = fn0; f1 = fn1;
        }
        // epilogue: last band1 pair
        #pragma unroll
        for (int r = 0; r < 16; ++r)
            rmn1[r] = fminf(fminf(rmn1[r], c0[r]), c1[r]);
    }

    // ---- register-folding butterfly row-min (17 swizzles/band) ----
    bool b0 = (l & 1), b1 = (l & 2), b2 = (l & 4), b3 = (l & 8);

#define FOLD(v)                                                                \
    {                                                                          \
        _Pragma("unroll")                                                      \
        for (int i = 0; i < 8; ++i) {                                          \
            float send = b0 ? v[i] : v[i + 8];                                 \
            float recv = __shfl_xor(send, 1);                                  \
            v[i] = fminf(b0 ? v[i + 8] : v[i], recv);                          \
        }                                                                      \
        _Pragma("unroll")                                                      \
        for (int i = 0; i < 4; ++i) {                                          \
            float send = b1 ? v[i] : v[i + 4];                                 \
            float recv = __shfl_xor(send, 2);                                  \
            v[i] = fminf(b1 ? v[i + 4] : v[i], recv);                          \
        }                                                                      \
        _Pragma("unroll")                                                      \
        for (int i = 0; i < 2; ++i) {                                          \
            float send = b2 ? v[i] : v[i + 2];                                 \
            float recv = __shfl_xor(send, 4);                                  \
            v[i] = fminf(b2 ? v[i + 2] : v[i], recv);                          \
        }                                                                      \
        {                                                                      \
            float send = b3 ? v[0] : v[1];                                     \
            float recv = __shfl_xor(send, 8);                                  \
            v[0] = fminf(b3 ? v[1] : v[0], recv);                              \
        }                                                                      \
        v[0] = fminf(v[0], __shfl_xor(v[0], 16));                              \
    }

    FOLD(rmn0);
    FOLD(rmn1);
#undef FOLD

    // lane g = l&15 holds reg rr = bitrev4(g); row-in-band = (rr&3)+8*(rr>>2)+4*kh
    // store CLAMPED row-min into quarter-contiguous layout [dirb][row][half]
    if ((l & 16) == 0) {
        int g = l & 15;
        int rr = ((g & 1) << 3) | ((g & 2) << 1) | ((g & 4) >> 1) | ((g & 8) >> 3);
        int rowin = (rr & 3) + 8 * (rr >> 2) + 4 * kh;
        size_t rowbase = ((size_t)dirb << 12) + rowgroup * 512;
        rfin[((rowbase + (w * 2 + 0) * 32 + rowin) << 2) + half] = fmaxf(rmn0[0], 0.0f);
        rfin[((rowbase + (w * 2 + 1) * 32 + rowin) << 2) + half] = fmaxf(rmn1[0], 0.0f);
    }
}

// ---------------------------------------------------------------------------
// Combine: 256 blocks = (dirb(16), slice(16)). One row per thread: a single
// COALESCED float4 load (the 4 clamped quarter-mins), 3-op min tree,
// fixed-order block sum -> pb[cb] + token flag. Block 0 spins on all 256
// flags (one per thread, R9/R12-proven) and finalizes out[0].
// Bit-identical every replay -> deterministic.
// ---------------------------------------------------------------------------
__global__ __launch_bounds__(256) void combine_kernel(
        const float4* __restrict__ rfin4, float* __restrict__ pb,
        unsigned* __restrict__ flags, float* __restrict__ out) {
    __shared__ float ws[4];
    __shared__ float sh[256 + 16];
    int cb = blockIdx.x;               // 0..255
    int dirb = cb >> 4, slice = cb & 15;
    int row = slice * 256 + threadIdx.x;
    float4 v = rfin4[((size_t)dirb << 12) + row];
    float s = fminf(fminf(v.x, v.y), fminf(v.z, v.w));   // already clamped
    for (int off = 32; off > 0; off >>= 1) s += __shfl_down(s, off);
    int wid = threadIdx.x >> 6, lane = threadIdx.x & 63;
    if (lane == 0) ws[wid] = s;
    __syncthreads();
    if (threadIdx.x == 0) {
        float t = ws[0] + ws[1] + ws[2] + ws[3];
        atomicExch((unsigned*)(pb + cb), __float_as_uint(t));
        __threadfence();
        atomicExch(flags + cb, flag_token(cb));
    }

    if (cb == 0) {
        __syncthreads();
        int t = threadIdx.x;               // 256 threads, one flag each
        unsigned want = flag_token(t);
        while (atomicAdd(flags + t, 0u) != want) {
            __builtin_amdgcn_s_sleep(1);
        }
        sh[t] = __uint_as_float(atomicAdd((unsigned*)(pb + t), 0u));
        __syncthreads();
        if (t < 16) {
            float a = 0.0f;
            #pragma unroll
            for (int c = 0; c < 16; ++c) a += sh[t * 16 + c];
            sh[256 + t] = a;
        }
        __syncthreads();
        if (t == 0) {
            float acc = 0.0f;
            #pragma unroll
            for (int bb = 0; bb < BATCH; ++bb)
                acc += fmaxf(sh[256 + bb], sh[256 + 8 + bb]);
            out[0] = acc * (1.0f / (float)NPTS) * (1.0f / (float)BATCH);
        }
    }
}

extern "C" void kernel_launch(void* const* d_in, const int* in_sizes, int n_in,
                              void* d_out, int out_size, void* d_ws, size_t ws_size,
                              hipStream_t stream) {
    const float* ori = (const float*)d_in[0];
    const float* adv = (const float*)d_in[1];
    float* out = (float*)d_out;

    // ws: rfin[16 dirb][4096 row][4 quarter] floats (1 MB) | pb[256] | flags[256]
    float* rfin = (float*)d_ws;
    float* pb = rfin + (size_t)16 * NPTS * NH;
    unsigned* flags = (unsigned*)(pb + 256);

    chamfer_partial<<<16 * NRG * NH, BLK, 0, stream>>>(ori, adv, rfin);
    combine_kernel<<<256, 256, 0, stream>>>((const float4*)rfin, pb, flags, out);
}

// Round 26
// 19.227 us; speedup vs baseline: 1.1414x; 1.1296x over previous
//
#include <hip/hip_runtime.h>
#include <float.h>

#define BATCH 8
#define NPTS 4096
#define BLK 512               // 8 waves
#define THALF 1024            // targets per block (one quarter)
#define NH 4                  // target quarters
#define NRG 8                 // rowgroups of 512 rows

typedef __attribute__((ext_vector_type(8))) short short8;      // 8 bf16
typedef __attribute__((ext_vector_type(16))) float floatx16;   // 32x32 MFMA acc

union U4S8 { uint4 u; short8 s; };
__device__ inline short8 asS8(uint4 u) { U4S8 t; t.u = u; return t.s; }

// round-to-nearest-even f32 -> bf16 bits
__device__ inline unsigned short f2bf(float f) {
    unsigned u = __float_as_uint(f);
    return (unsigned short)((u + 0x7FFFu + ((u >> 16) & 1u)) >> 16);
}
__device__ inline float bf2f(unsigned short h) {
    return __uint_as_float(((unsigned)h) << 16);
}
__device__ inline unsigned flag_token(int i) {
    return 0x9E3779B9u * (unsigned)(i + 7);   // never 0xAAAAAAAA poison
}

#define SBAR() __builtin_amdgcn_sched_barrier(0)

// ---------------------------------------------------------------------------
// CHAMPION (R22, 18.9us, absmax 0.0) — byte-identical revert.
// R24 (symmetric col-min) and R25 (quarter-interleaved rfin + 256-block
// combine) both regressed to ~21.8; the combine path was never the
// bottleneck and main's epilogue stores must stay band-coalesced.
// Main: grid = 512 = (dirb(16), rowgroup(8), quarter(4)); 8 waves x 2 bands
// of 32 rows; both kh-variant B-frags precomputed in LDS (32 KB); deferred
// cross-band MFMA pipeline with sched_barrier(0) phase pins; K=16 hi/lo
// bf16 encoding folds |q|^2+|t|^2-2q.t into one mfma_f32_32x32x16_bf16;
// C/D row = (r&3)+8*(r>>2)+4*kh (verified m74/m101). Register-folding
// butterfly row-min (17 swizzles/band), band-coalesced stores.
// ---------------------------------------------------------------------------
__global__ __launch_bounds__(BLK, 4) void chamfer_partial(
        const float* __restrict__ ori, const float* __restrict__ adv,
        float* __restrict__ rfin) {
    __shared__ uint4 fr[2 * THALF];   // 32 KB: [kh][target]

    int bx = blockIdx.x;               // 0..511
    int half = bx & (NH - 1);
    int rowgroup = (bx >> 2) & (NRG - 1);
    int dirb = bx >> 5;                // 0..15
    int b = dirb & 7;
    int dir = dirb >> 3;

    const float* qsrc = dir ? adv : ori;   // dir0: ori->adv, dir1: adv->ori
    const float* tsrc = dir ? ori : adv;

    // ---- stage this quarter's 1024 targets as BOTH B-frag variants ----
    {
        const float* tx = tsrc + (b * 3 + 0) * NPTS;
        const float* ty = tsrc + (b * 3 + 1) * NPTS;
        const float* tz = tsrc + (b * 3 + 2) * NPTS;
        #pragma unroll
        for (int i = 0; i < THALF / BLK; ++i) {
            int p = threadIdx.x + i * BLK;
            int m = half * THALF + p;
            float x = tx[m], y = ty[m], z = tz[m];
            float n2 = fmaf(x, x, fmaf(y, y, z * z));
            unsigned short hx = f2bf(x), hy = f2bf(y), hz = f2bf(z);
            unsigned short lx = f2bf(x - bf2f(hx));
            unsigned short ly = f2bf(y - bf2f(hy));
            unsigned short lz = f2bf(z - bf2f(hz));
            unsigned short h2 = f2bf(n2);
            unsigned short l2 = f2bf(n2 - bf2f(h2));
            uint4 v0;   // kh=0: B rows 0..7 = [thi(3), tlo(3), n2h, n2l]
            v0.x = (unsigned)hx | ((unsigned)hy << 16);
            v0.y = (unsigned)hz | ((unsigned)lx << 16);
            v0.z = (unsigned)ly | ((unsigned)lz << 16);
            v0.w = (unsigned)h2 | ((unsigned)l2 << 16);
            uint4 v1;   // kh=1: B rows 8..15 = [thi(3), 1, 1, 0,0,0]
            v1.x = v0.x;
            v1.y = (unsigned)hz | (0x3F80u << 16);
            v1.z = 0x00003F80u;
            v1.w = 0u;
            fr[p] = v0;
            fr[THALF + p] = v1;
        }
    }

    // ---- per-wave A fragments: 2 bands of 32 rows ----
    int w = threadIdx.x >> 6;          // wave 0..7
    int l = threadIdx.x & 63;
    int lrow = l & 31;
    int kh = l >> 5;

    short8 afrag0, afrag1;
    #pragma unroll
    for (int bi = 0; bi < 2; ++bi) {
        int q = rowgroup * 512 + (w * 2 + bi) * 32 + lrow;
        float x = qsrc[(b * 3 + 0) * NPTS + q];
        float y = qsrc[(b * 3 + 1) * NPTS + q];
        float z = qsrc[(b * 3 + 2) * NPTS + q];
        float n2 = fmaf(x, x, fmaf(y, y, z * z));
        unsigned short hx = f2bf(x), hy = f2bf(y), hz = f2bf(z);
        unsigned short lx = f2bf(x - bf2f(hx));
        unsigned short ly = f2bf(y - bf2f(hy));
        unsigned short lz = f2bf(z - bf2f(hz));
        unsigned short h2 = f2bf(n2);
        unsigned short l2 = f2bf(n2 - bf2f(h2));
        unsigned short mhx = f2bf(-2.0f * bf2f(hx));
        unsigned short mhy = f2bf(-2.0f * bf2f(hy));
        unsigned short mhz = f2bf(-2.0f * bf2f(hz));
        unsigned short mlx = f2bf(-2.0f * bf2f(lx));
        unsigned short mly = f2bf(-2.0f * bf2f(ly));
        unsigned short mlz = f2bf(-2.0f * bf2f(lz));
        const unsigned short one = 0x3F80;
        union { unsigned short us[8]; short8 s8; } A;
        if (kh == 0) {
            A.us[0] = mhx; A.us[1] = mhy; A.us[2] = mhz;
            A.us[3] = mhx; A.us[4] = mhy; A.us[5] = mhz;
            A.us[6] = one; A.us[7] = one;
        } else {
            A.us[0] = mlx; A.us[1] = mly; A.us[2] = mlz;
            A.us[3] = h2;  A.us[4] = l2;
            A.us[5] = 0;   A.us[6] = 0;   A.us[7] = 0;
        }
        if (bi == 0) afrag0 = A.s8; else afrag1 = A.s8;
    }
    __syncthreads();

    floatx16 zero, rmn0, rmn1;
    #pragma unroll
    for (int r = 0; r < 16; ++r) { zero[r] = 0.0f; rmn0[r] = FLT_MAX; rmn1[r] = FLT_MAX; }

    const uint4* tp = fr + kh * THALF + lrow;

    // ---- deferred cross-band pipeline, schedule pinned via sched_barrier ----
    {
        uint4 f0 = tp[0], f1 = tp[1 << 5];
        floatx16 a0 = __builtin_amdgcn_mfma_f32_32x32x16_bf16(afrag0, asS8(f0), zero, 0, 0, 0);
        floatx16 a1 = __builtin_amdgcn_mfma_f32_32x32x16_bf16(afrag0, asS8(f1), zero, 0, 0, 0);
        uint4 fn0 = tp[2 << 5], fn1 = tp[3 << 5];
        #pragma unroll
        for (int r = 0; r < 16; ++r)
            rmn0[r] = fminf(fminf(rmn0[r], a0[r]), a1[r]);   // -> v_min3
        floatx16 c0 = __builtin_amdgcn_mfma_f32_32x32x16_bf16(afrag1, asS8(f0), zero, 0, 0, 0);
        floatx16 c1 = __builtin_amdgcn_mfma_f32_32x32x16_bf16(afrag1, asS8(f1), zero, 0, 0, 0);
        f0 = fn0; f1 = fn1;

        #pragma unroll 1
        for (int ct = 2; ct < 32; ct += 2) {
            // phase 1: consume band1 of previous tile-pair
            #pragma unroll
            for (int r = 0; r < 16; ++r)
                rmn1[r] = fminf(fminf(rmn1[r], c0[r]), c1[r]);
            SBAR();
            // phase 2: issue band0 of current pair
            a0 = __builtin_amdgcn_mfma_f32_32x32x16_bf16(afrag0, asS8(f0), zero, 0, 0, 0);
            a1 = __builtin_amdgcn_mfma_f32_32x32x16_bf16(afrag0, asS8(f1), zero, 0, 0, 0);
            SBAR();
            // phase 3: prefetch next pair (wraps harmlessly on last iter)
            int nt = (ct + 2) & 31;
            fn0 = tp[nt << 5]; fn1 = tp[(nt + 1) << 5];
            SBAR();
            // phase 4: consume band0 (MFMA latency hidden by phase 3)
            #pragma unroll
            for (int r = 0; r < 16; ++r)
                rmn0[r] = fminf(fminf(rmn0[r], a0[r]), a1[r]);
            SBAR();
            // phase 5: issue band1 of current pair (consumed next iteration)
            c0 = __builtin_amdgcn_mfma_f32_32x32x16_bf16(afrag1, asS8(f0), zero, 0, 0, 0);
            c1 = __builtin_amdgcn_mfma_f32_32x32x16_bf16(afrag1, asS8(f1), zero, 0, 0, 0);
            SBAR();
            f0 = fn0; f1 = fn1;
        }
        // epilogue: last band1 pair
        #pragma unroll
        for (int r = 0; r < 16; ++r)
            rmn1[r] = fminf(fminf(rmn1[r], c0[r]), c1[r]);
    }

    // ---- register-folding butterfly row-min (17 swizzles/band) ----
    bool b0 = (l & 1), b1 = (l & 2), b2 = (l & 4), b3 = (l & 8);

#define FOLD(v)                                                                \
    {                                                                          \
        _Pragma("unroll")                                                      \
        for (int i = 0; i < 8; ++i) {                                          \
            float send = b0 ? v[i] : v[i + 8];                                 \
            float recv = __shfl_xor(send, 1);                                  \
            v[i] = fminf(b0 ? v[i + 8] : v[i], recv);                          \
        }                                                                      \
        _Pragma("unroll")                                                      \
        for (int i = 0; i < 4; ++i) {                                          \
            float send = b1 ? v[i] : v[i + 4];                                 \
            float recv = __shfl_xor(send, 2);                                  \
            v[i] = fminf(b1 ? v[i + 4] : v[i], recv);                          \
        }                                                                      \
        _Pragma("unroll")                                                      \
        for (int i = 0; i < 2; ++i) {                                          \
            float send = b2 ? v[i] : v[i + 2];                                 \
            float recv = __shfl_xor(send, 4);                                  \
            v[i] = fminf(b2 ? v[i + 2] : v[i], recv);                          \
        }                                                                      \
        {                                                                      \
            float send = b3 ? v[0] : v[1];                                     \
            float recv = __shfl_xor(send, 8);                                  \
            v[0] = fminf(b3 ? v[1] : v[0], recv);                              \
        }                                                                      \
        v[0] = fminf(v[0], __shfl_xor(v[0], 16));                              \
    }

    FOLD(rmn0);
    FOLD(rmn1);
#undef FOLD

    // lane g = l&15 holds reg rr = bitrev4(g); row-in-band = (rr&3)+8*(rr>>2)+4*kh
    if ((l & 16) == 0) {
        int g = l & 15;
        int rr = ((g & 1) << 3) | ((g & 2) << 1) | ((g & 4) >> 1) | ((g & 8) >> 3);
        int rowin = (rr & 3) + 8 * (rr >> 2) + 4 * kh;
        float* base = rfin + (((size_t)(dirb * NH + half)) << 12)
                    + rowgroup * 512;
        base[(w * 2 + 0) * 32 + rowin] = rmn0[0];
        base[(w * 2 + 1) * 32 + rowin] = rmn1[0];
    }
}

// ---------------------------------------------------------------------------
// Combine (R17/R22-proven): 64 blocks = (dirb(16), slice(4)). Each thread: 4
// rows, min over the 4 quarter planes, clamp >=0, fixed-order sum -> pb[cb]
// + token flag. Block 0 spins on all 64 flags and finalizes out[0].
// Bit-identical every replay -> deterministic.
// ---------------------------------------------------------------------------
__global__ __launch_bounds__(256) void combine_kernel(
        const float* __restrict__ rfin, float* __restrict__ pb,
        unsigned* __restrict__ flags, float* __restrict__ out) {
    __shared__ float ws[4];
    __shared__ float sh[64 + 16];
    int cb = blockIdx.x;               // 0..63
    int dirb = cb >> 2, slice = cb & 3;
    const float* p = rfin + (((size_t)dirb * NH) << 12);
    float s = 0.0f;
    #pragma unroll
    for (int k = 0; k < 4; ++k) {
        int row = slice * 1024 + k * 256 + threadIdx.x;
        float m = fminf(fminf(p[row], p[(1 << 12) + row]),
                        fminf(p[(2 << 12) + row], p[(3 << 12) + row]));
        s += fmaxf(m, 0.0f);
    }
    for (int off = 32; off > 0; off >>= 1) s += __shfl_down(s, off);
    int wid = threadIdx.x >> 6, lane = threadIdx.x & 63;
    if (lane == 0) ws[wid] = s;
    __syncthreads();
    if (threadIdx.x == 0) {
        float t = ws[0] + ws[1] + ws[2] + ws[3];
        atomicExch((unsigned*)(pb + cb), __float_as_uint(t));
        __threadfence();
        atomicExch(flags + cb, flag_token(cb));
    }

    if (cb == 0) {
        __syncthreads();
        int t = threadIdx.x;
        if (t < 64) {
            unsigned want = flag_token(t);
            while (atomicAdd(flags + t, 0u) != want) {
                __builtin_amdgcn_s_sleep(1);
            }
            sh[t] = __uint_as_float(atomicAdd((unsigned*)(pb + t), 0u));
        }
        __syncthreads();
        if (t < 16) {
            sh[64 + t] = sh[t * 4] + sh[t * 4 + 1] + sh[t * 4 + 2] + sh[t * 4 + 3];
        }
        __syncthreads();
        if (t == 0) {
            float acc = 0.0f;
            #pragma unroll
            for (int bb = 0; bb < BATCH; ++bb)
                acc += fmaxf(sh[64 + bb], sh[64 + 8 + bb]);
            out[0] = acc * (1.0f / (float)NPTS) * (1.0f / (float)BATCH);
        }
    }
}

extern "C" void kernel_launch(void* const* d_in, const int* in_sizes, int n_in,
                              void* d_out, int out_size, void* d_ws, size_t ws_size,
                              hipStream_t stream) {
    const float* ori = (const float*)d_in[0];
    const float* adv = (const float*)d_in[1];
    float* out = (float*)d_out;

    // ws: rfin[16 dirb][4 quarter][4096 row] floats (1 MB) | pb[64] | flags[64]
    float* rfin = (float*)d_ws;
    float* pb = rfin + (size_t)16 * NH * NPTS;
    unsigned* flags = (unsigned*)(pb + 64);

    chamfer_partial<<<16 * NRG * NH, BLK, 0, stream>>>(ori, adv, rfin);
    combine_kernel<<<64, 256, 0, stream>>>(rfin, pb, flags, out);
}